// Round 2
// baseline (589.289 us; speedup 1.0000x reference)
//
#include <hip/hip_runtime.h>

// Problem constants (from reference)
#define NB      128
#define ND      8
#define NK      8
#define TLEN    512
#define NSTEPS  496
#define WPB     8      // waves (=batches) per block -> 2 waves per SIMD
#define XRING   80     // x ring columns per wave

#define INVLN2f 1.44269504088896340736f

__device__ __forceinline__ float fexp(float x) { return __expf(x); }
__device__ __forceinline__ float flog(float x) { return __logf(x); }
__device__ __forceinline__ float frcp(float x) { return __builtin_amdgcn_rcpf(x); }
__device__ __forceinline__ float elur(float x) { return x > 0.f ? x : fexp(x) - 1.f; }

#if defined(__has_builtin)
#if __has_builtin(__builtin_amdgcn_exp2f)
#define fexp2(x) __builtin_amdgcn_exp2f(x)
#endif
#endif
#ifndef fexp2
#define fexp2(x) exp2f(x)
#endif

// DPP helpers. quad_perm 0xB1 = lane^1, 0x4E = lane^2, row_ror:4 acts as lane^4
// within a replicated-every-8 value; row_ror:N (0x120|N) rotates within 16-lane rows.
#define DPP_ROR4(v) __int_as_float(__builtin_amdgcn_mov_dpp(__float_as_int(v), 0x124, 0xF, 0xF, false))
#define DPP_X1(v)   __int_as_float(__builtin_amdgcn_mov_dpp(__float_as_int(v), 0xB1, 0xF, 0xF, false))
#define DPP_X2(v)   __int_as_float(__builtin_amdgcn_mov_dpp(__float_as_int(v), 0x4E, 0xF, 0xF, false))
#define DPP_RORN(v, ctrl) __int_as_float(__builtin_amdgcn_mov_dpp(__float_as_int(v), (ctrl), 0xF, 0xF, false))

#define RED8_MAX(m) { m = fmaxf(m, DPP_X1(m)); m = fmaxf(m, DPP_X2(m)); m = fmaxf(m, DPP_ROR4(m)); }
#define RED8_SUM(s) { s = s + DPP_X1(s); s = s + DPP_X2(s); s = s + DPP_ROR4(s); }

typedef unsigned int uint2v __attribute__((ext_vector_type(2)));
typedef float floatx2 __attribute__((ext_vector_type(2)));

__device__ __forceinline__ floatx2 f2(float t) { floatx2 r; r.x = t; r.y = t; return r; }

// v + v[lane^32] on all lanes, via VALU permlane32_swap (no DS pipe).
#if defined(__has_builtin)
#if __has_builtin(__builtin_amdgcn_permlane32_swap)
#define HAVE_PLSWAP 1
#endif
#if __has_builtin(__builtin_amdgcn_permlane16_swap)
#define HAVE_PL16SWAP 1
#endif
#endif

#ifdef HAVE_PLSWAP
__device__ __forceinline__ float xhalfsum(float v) {
    unsigned int u = __float_as_uint(v);
    uint2v r = __builtin_amdgcn_permlane32_swap(u, u, false, false);
    return __uint_as_float(r[0]) + __uint_as_float(r[1]);
}
#else
__device__ __forceinline__ float xhalfsum(float v) { return v + __shfl_xor(v, 32); }
#endif

// Layout-B fixup: rows 0,1 (lanes 0-31) keep own value; rows 2,3 take lane^16's.
// selr0 is a per-lane runtime-probed select (exact bits, no arithmetic).
#ifdef HAVE_PL16SWAP
#define TOB(v) ({                                                                  \
    float _v = (v);                                                                \
    unsigned _u = __float_as_uint(_v);                                             \
    uint2v _r = __builtin_amdgcn_permlane16_swap(_u, _u, false, false);            \
    float _o = __uint_as_float(selr0 ? _r[0] : _r[1]);                             \
    (lane < 32) ? _v : _o; })
#else
#define TOB(v) ({                                                                  \
    float _v = (v);                                                                \
    float _o = __uint_as_float((unsigned)__builtin_amdgcn_ds_swizzle(              \
                   (int)__float_as_uint(_v), 0x401F));                             \
    (lane < 32) ? _v : _o; })
#endif

// Dual 16-term rotation dot (new-tap in .x, old-tap in .y). vB holds, at row
// slot s, h[jbase+s]; the 15 row_ror DPP movs are independent (all off vB).
// Weights pre-ordered per lane so wp[r] pairs with rotation r.
__device__ __forceinline__ floatx2 rotdot16x2p(float vB, const floatx2* __restrict__ wp) {
    float t1 = DPP_RORN(vB, 0x121), t2 = DPP_RORN(vB, 0x122), t3 = DPP_RORN(vB, 0x123);
    float t4 = DPP_RORN(vB, 0x124), t5 = DPP_RORN(vB, 0x125), t6 = DPP_RORN(vB, 0x126);
    float t7 = DPP_RORN(vB, 0x127), t8 = DPP_RORN(vB, 0x128), t9 = DPP_RORN(vB, 0x129);
    float tA = DPP_RORN(vB, 0x12A), tB = DPP_RORN(vB, 0x12B), tC = DPP_RORN(vB, 0x12C);
    float tD = DPP_RORN(vB, 0x12D), tE = DPP_RORN(vB, 0x12E), tF = DPP_RORN(vB, 0x12F);
    floatx2 a0 = wp[0] * f2(vB);
    floatx2 a1 = wp[1] * f2(t1);
    floatx2 a2 = wp[2] * f2(t2);
    floatx2 a3 = wp[3] * f2(t3);
    a0 = __builtin_elementwise_fma(wp[4],  f2(t4), a0);
    a1 = __builtin_elementwise_fma(wp[5],  f2(t5), a1);
    a2 = __builtin_elementwise_fma(wp[6],  f2(t6), a2);
    a3 = __builtin_elementwise_fma(wp[7],  f2(t7), a3);
    a0 = __builtin_elementwise_fma(wp[8],  f2(t8), a0);
    a1 = __builtin_elementwise_fma(wp[9],  f2(t9), a1);
    a2 = __builtin_elementwise_fma(wp[10], f2(tA), a2);
    a3 = __builtin_elementwise_fma(wp[11], f2(tB), a3);
    a0 = __builtin_elementwise_fma(wp[12], f2(tC), a0);
    a1 = __builtin_elementwise_fma(wp[13], f2(tD), a1);
    a2 = __builtin_elementwise_fma(wp[14], f2(tE), a2);
    a3 = __builtin_elementwise_fma(wp[15], f2(tF), a3);
    return (a0 + a1) + (a2 + a3);
}

// One scan step. LOFFv = ring column of x for this step (l = LOFFv + tap).
// All cross-lane matvec transport is VALU (DPP + permlane); the per-step LDS
// reads (x ring, gls chunk) are address-static and prefetchable.
#define STEP(qv, LOFFv, S1, S2, S3, DO_OUT)                                       \
  {                                                                               \
    const int q_ = (qv);                                                          \
    float g2_own = 0.f;                                                           \
    if (DO_OUT) g2_own = gw[(((q_) - 15) & 63) * NK + o3];                        \
    const float4* _xq = (const float4*)&xw[((LOFFv) + tap) * 8];                  \
    float4 _xa = _xq[0], _xb = _xq[1];                                            \
    /* layer 0: all contributions pre-folded into XZ */                           \
    float o0v = elur(XZ);                                                         \
    /* layer 1 */                                                                 \
    float v0B = TOB(o0v);                                                         \
    floatx2 d1 = rotdot16x2p(v0B, w1p);                                           \
    float o1v = elur(xhalfsum(d1.x + P1[S1]));                                    \
    P1[S1] = b1h + d1.y;                                                          \
    /* layer 2 */                                                                 \
    float v1B = TOB(o1v);                                                         \
    floatx2 d2 = rotdot16x2p(v1B, w2p);                                           \
    float o2v = elur(xhalfsum(d2.x + P2[S2]));                                    \
    P2[S2] = b2h + d2.y;                                                          \
    /* layer 3 */                                                                 \
    float v2B = TOB(o2v);                                                         \
    floatx2 d3 = rotdot16x2p(v2B, w3p);                                           \
    float a3m = elur(xhalfsum(d3.x + P3[S3]));                                    \
    P3[S3] = b3h + d3.y;                                                          \
    if (DO_OUT) {                                                                 \
      /* feedback gumbel-softmax: single exp2, no max-sub */                      \
      float F = fexp2(fmaf(a3m, klog, g2_own));                                   \
      float S = F; RED8_SUM(S);                                                   \
      float r2 = frcp(S);                                                         \
      /* rotate F across the 8-group; dot with rotation-ordered z-weights */      \
      float rt1 = DPP_RORN(F, 0x121), rt2 = DPP_RORN(F, 0x122);                   \
      float rt3 = DPP_RORN(F, 0x123), rt4 = DPP_RORN(F, 0x124);                   \
      float rt5 = DPP_RORN(F, 0x125), rt6 = DPP_RORN(F, 0x126);                   \
      float rt7 = DPP_RORN(F, 0x127);                                             \
      float na = wznrot[0] * F,   nb = wznrot[1] * rt1;                           \
      float nc = wznrot[2] * rt2, nd = wznrot[3] * rt3;                           \
      na = fmaf(wznrot[4], rt4, na); nb = fmaf(wznrot[5], rt5, nb);               \
      nc = fmaf(wznrot[6], rt6, nc); nd = fmaf(wznrot[7], rt7, nd);               \
      float oa = wzorot[0] * F,   ob = wzorot[1] * rt1;                           \
      float oc = wzorot[2] * rt2, od = wzorot[3] * rt3;                           \
      oa = fmaf(wzorot[4], rt4, oa); ob = fmaf(wzorot[5], rt5, ob);               \
      oc = fmaf(wzorot[6], rt6, oc); od = fmaf(wzorot[7], rt7, od);               \
      ZN   = ((na + nb) + (nc + nd)) * r2;   /* wzn.y(q) -> XZ at q+1 */          \
      ZQ2n = ((oa + ob) + (oc + od)) * r2;   /* wzo.y(q) -> XZ at q+2 */          \
      /* off-path: log-softmax output */                                          \
      float mx = a3m; RED8_MAX(mx);                                               \
      float e = fexp(a3m - mx);                                                   \
      float se = e; RED8_SUM(se);                                                 \
      float lse = mx + flog(se);                                                  \
      if (lane < 8) {                                                             \
        outg[zoff + lane * TLEN + q_ + 1]       = F * r2;                         \
        outg[qoff + lane * NSTEPS + (q_ - 15)]  = a3m - lse;                      \
      }                                                                           \
    }                                                                             \
    /* park x-part + z-feedback for step q_+1: ZQ2 == wzo.y(q_-1) here */         \
    {                                                                             \
      float s0 = fmaf(wxr[0], _xa.x, fmaf(wxr[1], _xa.y, 0.f));                   \
      float s1 = fmaf(wxr[2], _xa.z, fmaf(wxr[3], _xa.w, 0.f));                   \
      float s2 = fmaf(wxr[4], _xb.x, fmaf(wxr[5], _xb.y, 0.f));                   \
      float s3 = fmaf(wxr[6], _xb.z, fmaf(wxr[7], _xb.w, 0.f));                   \
      float xp = (s0 + s1) + (s2 + s3);                                           \
      XZ = (xhalfsum(xp) + b0r + ZQ2) + ZN;                                       \
      ZQ2 = ZQ2n;                                                                 \
    }                                                                             \
  }

__global__ __launch_bounds__(512, 2)
void regime_scan_kernel(const float* __restrict__ xg,
                        const float* __restrict__ tempg,
                        const float* __restrict__ ug,
                        const float* __restrict__ w0g,
                        const float* __restrict__ b0g,
                        const float* __restrict__ w1g,
                        const float* __restrict__ b1g,
                        const float* __restrict__ w2g,
                        const float* __restrict__ b2g,
                        const float* __restrict__ w3g,
                        const float* __restrict__ b3g,
                        float* __restrict__ outg)
{
    // Per-wave rolling LDS windows; no cross-wave sharing, no barriers.
    __shared__ __align__(16) float xbuf[WPB][XRING][8];   // 20.0 KB
    __shared__ __align__(16) float glsw[WPB][64 * NK];    // 16.0 KB

    const int lane = threadIdx.x & 63;
    const int wid  = threadIdx.x >> 6;
    const int b    = blockIdx.x * WPB + wid;   // one batch element per wave
    const int c    = lane & 31;            // output channel owned (layers 0-2)
    const int o3   = lane & 7;             // layer-3 channel owned
    const int tap  = (lane < 32) ? 1 : 0;  // x-park tap role
    const int s    = lane & 15;            // slot within 16-lane DPP row
    const int rowq = lane >> 4;            // DPP row 0..3
    // rows hold j-halves [lo,hi,hi,lo] after the TOB fixup
    const int jbase = ((rowq ^ (rowq >> 1)) & 1) << 4;

    float* xw = &xbuf[wid][0][0];
    float* gw = &glsw[wid][0];

    // ---- runtime probe (uniform): row_ror direction on this HW ----
    int dir;
    {
        int l15 = lane & 15;
        int rr1 = __builtin_amdgcn_mov_dpp(l15, 0x121, 0xF, 0xF, false); // row_ror:1
        dir = (rr1 == ((l15 + 1) & 15)) ? 1 : -1;
    }
    // ---- runtime probe (per-lane): which permlane16_swap slot is lane^16 ----
    int selr0 = 0;
#ifdef HAVE_PL16SWAP
    {
        unsigned li = (unsigned)lane;
        uint2v pr = __builtin_amdgcn_permlane16_swap(li, li, false, false);
        selr0 = (pr[0] == (li ^ 16u)) ? 1 : 0;
    }
#endif

    // ---- per-lane weights ----
    float wznrot[8], wzorot[8];
    #pragma unroll
    for (int r = 0; r < 8; ++r) {
        int ch = (o3 + dir * r) & 7;
        wznrot[r] = w0g[c * 32 + (8 + ch) * 2 + 1];
        wzorot[r] = w0g[c * 32 + (8 + ch) * 2 + 0];
    }
    float wxr[8];
    #pragma unroll
    for (int d = 0; d < 8; ++d) wxr[d] = w0g[c * 32 + d * 2 + tap];
    floatx2 w1p[16], w2p[16], w3p[16];
    #pragma unroll
    for (int r = 0; r < 16; ++r) {
        int jj = jbase + ((s + dir * r) & 15);
        w1p[r].x = w1g[c  * 64 + jj * 2 + 1];
        w1p[r].y = w1g[c  * 64 + jj * 2 + 0];
        w2p[r].x = w2g[c  * 64 + jj * 2 + 1];
        w2p[r].y = w2g[c  * 64 + jj * 2 + 0];
        w3p[r].x = w3g[o3 * 64 + jj * 2 + 1];
        w3p[r].y = w3g[o3 * 64 + jj * 2 + 0];
    }
    const float b0r  = b0g[c];
    const float b1h  = 0.5f * b1g[c];      // half-bias: completed by xhalfsum
    const float b2h  = 0.5f * b2g[c];
    const float b3h  = 0.5f * b3g[o3];
    const float tinv = frcp(tempg[0]);
    const float klog = tinv * INVLN2f;     // a3 coefficient in exp2 domain

    // ---- prologue: x ring chunk 0 (covers padded cols p=0..79; l == p) ----
    const float* xb = xg + b * (ND * TLEN);
    for (int idx = lane; idx < XRING * ND; idx += 64) {
        int lc = idx >> 3, d = idx & 7;
        int t = lc - 15;                           // t <= 64 < TLEN always
        xw[idx] = (t >= 0) ? xb[d * TLEN + t] : 0.f;
    }
    // ---- prologue: Gumbel chunk 0 (steps 0..63), g2 = g * tinv / ln2 ----
    for (int idx = lane; idx < 64 * NK; idx += 64) {
        int st = idx >> 3, k = idx & 7;
        float uu = ug[st * (NB * NK) + b * NK + k];
        gw[idx] = -flog(-flog(uu + 1e-10f) + 1e-10f) * klog;
    }
    // ---- z_all[:, :, 0:16] = 0 ----
    const int zoff = b * (NK * TLEN);
    const int qoff = NB * NK * TLEN + b * (NK * NSTEPS);
    for (int idx = lane; idx < NK * 16; idx += 64) {
        outg[zoff + (idx >> 4) * TLEN + (idx & 15)] = 0.f;
    }

    // ---- state ----
    float P1[2] = { b1h, b1h };
    float P2[4] = { b2h, b2h, b2h, b2h };
    float P3[8];
    #pragma unroll
    for (int k = 0; k < 8; ++k) P3[k] = b3h;
    float ZQ2 = 0.f, ZQ2n = 0.f, ZN = 0.f;
    float XZ;
    {
        const float4* xq = (const float4*)&xw[tap * 8];   // l == p == tap
        float4 xa = xq[0], xbv = xq[1];
        float s0 = fmaf(wxr[0], xa.x, fmaf(wxr[1], xa.y, 0.f));
        float s1 = fmaf(wxr[2], xa.z, fmaf(wxr[3], xa.w, 0.f));
        float s2 = fmaf(wxr[4], xbv.x, fmaf(wxr[5], xbv.y, 0.f));
        float s3 = fmaf(wxr[6], xbv.z, fmaf(wxr[7], xbv.w, 0.f));
        XZ = xhalfsum((s0 + s1) + (s2 + s3)) + b0r;   // z = 0 at start
    }

    // ---- warmup q=1..14 (z stays zero; ring l == q+tap) ----
    #pragma unroll
    for (int q = 1; q <= 14; ++q) STEP(q, q, q & 1, q & 3, q & 7, 0);

    // ---- main loop: 8 chunks of <=64 steps, per-wave ring refill ----
    for (int chk = 0; chk < 8; ++chk) {
        const int B0 = 15 + chk * 64;        // first q of chunk
        if (chk > 0) {
            // x refill: 65 cols, p = B0 + lc  ->  ring l = lc
            for (int idx = lane; idx < 65 * ND; idx += 64) {
                int lc = idx >> 3, d = idx & 7;
                int t = B0 + lc - 15;
                xw[idx] = (t < TLEN) ? xb[d * TLEN + t] : 0.f;
            }
            // gls refill: steps c0..c0+63
            const int c0 = chk * 64;
            for (int idx = lane; idx < 64 * NK; idx += 64) {
                int st = c0 + (idx >> 3), k = idx & 7;
                float g2v = 0.f;
                if (st < NSTEPS) {
                    float uu = ug[st * (NB * NK) + b * NK + k];
                    g2v = -flog(-flog(uu + 1e-10f) + 1e-10f) * klog;
                }
                gw[idx] = g2v;
            }
        }
        const int jmax = (chk == 7) ? 6 : 8;     // last chunk: 48 steps
        const int lb   = (chk == 0) ? 15 : 0;    // chunk0 reuses prologue fill
        for (int j = 0; j < jmax; ++j) {
            const int q0 = B0 + j * 8;
            const int l0 = lb + j * 8;
            #pragma unroll
            for (int u = 0; u < 8; ++u) {
                STEP(q0 + u, l0 + u, (15 + u) & 1, (15 + u) & 3, (15 + u) & 7, 1);
            }
        }
    }
}

extern "C" void kernel_launch(void* const* d_in, const int* in_sizes, int n_in,
                              void* d_out, int out_size, void* d_ws, size_t ws_size,
                              hipStream_t stream) {
    (void)in_sizes; (void)n_in; (void)out_size; (void)d_ws; (void)ws_size;
    regime_scan_kernel<<<dim3(NB / WPB), dim3(WPB * 64), 0, stream>>>(
        (const float*)d_in[0],   // x
        (const float*)d_in[1],   // temp
        (const float*)d_in[2],   // u
        (const float*)d_in[3],   // w0
        (const float*)d_in[4],   // b0
        (const float*)d_in[5],   // w1
        (const float*)d_in[6],   // b1
        (const float*)d_in[7],   // w2
        (const float*)d_in[8],   // b2
        (const float*)d_in[9],   // w3
        (const float*)d_in[10],  // b3
        (float*)d_out);
}

// Round 3
// 360.364 us; speedup vs baseline: 1.6353x; 1.6353x over previous
//
#include <hip/hip_runtime.h>

// Problem constants (from reference)
#define NB      128
#define ND      8
#define NK      8
#define TLEN    512
#define NSTEPS  496

#define INVLN2f 1.44269504088896340736f

__device__ __forceinline__ float fexp(float x) { return __expf(x); }
__device__ __forceinline__ float flog(float x) { return __logf(x); }
__device__ __forceinline__ float frcp(float x) { return __builtin_amdgcn_rcpf(x); }
__device__ __forceinline__ float elur(float x) { return x > 0.f ? x : fexp(x) - 1.f; }

#if defined(__has_builtin)
#if __has_builtin(__builtin_amdgcn_exp2f)
#define fexp2(x) __builtin_amdgcn_exp2f(x)
#endif
#endif
#ifndef fexp2
#define fexp2(x) exp2f(x)
#endif

// DPP helpers. quad_perm 0xB1 = lane^1, 0x4E = lane^2, row_ror:4 acts as lane^4
// within a replicated-every-8 value; row_ror:N (0x120|N) rotates within 16-lane rows.
#define DPP_ROR4(v) __int_as_float(__builtin_amdgcn_mov_dpp(__float_as_int(v), 0x124, 0xF, 0xF, false))
#define DPP_X1(v)   __int_as_float(__builtin_amdgcn_mov_dpp(__float_as_int(v), 0xB1, 0xF, 0xF, false))
#define DPP_X2(v)   __int_as_float(__builtin_amdgcn_mov_dpp(__float_as_int(v), 0x4E, 0xF, 0xF, false))
#define DPP_RORN(v, ctrl) __int_as_float(__builtin_amdgcn_mov_dpp(__float_as_int(v), (ctrl), 0xF, 0xF, false))

#define RED8_MAX(m) { m = fmaxf(m, DPP_X1(m)); m = fmaxf(m, DPP_X2(m)); m = fmaxf(m, DPP_ROR4(m)); }
#define RED8_SUM(s) { s = s + DPP_X1(s); s = s + DPP_X2(s); s = s + DPP_ROR4(s); }

typedef unsigned int uint2v __attribute__((ext_vector_type(2)));
typedef float floatx2 __attribute__((ext_vector_type(2)));

__device__ __forceinline__ floatx2 f2(float t) { floatx2 r; r.x = t; r.y = t; return r; }

// v + v[lane^32] on all lanes, via VALU permlane32_swap (no DS pipe).
#if defined(__has_builtin)
#if __has_builtin(__builtin_amdgcn_permlane32_swap)
#define HAVE_PLSWAP 1
#endif
#if __has_builtin(__builtin_amdgcn_permlane16_swap)
#define HAVE_PL16SWAP 1
#endif
#endif

#ifdef HAVE_PLSWAP
__device__ __forceinline__ float xhalfsum(float v) {
    unsigned int u = __float_as_uint(v);
    uint2v r = __builtin_amdgcn_permlane32_swap(u, u, false, false);
    return __uint_as_float(r[0]) + __uint_as_float(r[1]);
}
#else
__device__ __forceinline__ float xhalfsum(float v) { return v + __shfl_xor(v, 32); }
#endif

// Layout-B fixup: rows 0,1 (lanes 0-31) keep own value; rows 2,3 take lane^16's.
#ifdef HAVE_PL16SWAP
#define TOB(v) ({                                                                  \
    float _v = (v);                                                                \
    unsigned _u = __float_as_uint(_v);                                             \
    uint2v _r = __builtin_amdgcn_permlane16_swap(_u, _u, false, false);            \
    float _o = __uint_as_float(selr0 ? _r[0] : _r[1]);                             \
    (lane < 32) ? _v : _o; })
#else
#define TOB(v) ({                                                                  \
    float _v = (v);                                                                \
    float _o = __uint_as_float((unsigned)__builtin_amdgcn_ds_swizzle(              \
                   (int)__float_as_uint(_v), 0x401F));                             \
    (lane < 32) ? _v : _o; })
#endif

// Dual 16-term rotation dot (new-tap in .x, old-tap in .y).
__device__ __forceinline__ floatx2 rotdot16x2p(float vB, const floatx2* __restrict__ wp) {
    float t1 = DPP_RORN(vB, 0x121), t2 = DPP_RORN(vB, 0x122), t3 = DPP_RORN(vB, 0x123);
    float t4 = DPP_RORN(vB, 0x124), t5 = DPP_RORN(vB, 0x125), t6 = DPP_RORN(vB, 0x126);
    float t7 = DPP_RORN(vB, 0x127), t8 = DPP_RORN(vB, 0x128), t9 = DPP_RORN(vB, 0x129);
    float tA = DPP_RORN(vB, 0x12A), tB = DPP_RORN(vB, 0x12B), tC = DPP_RORN(vB, 0x12C);
    float tD = DPP_RORN(vB, 0x12D), tE = DPP_RORN(vB, 0x12E), tF = DPP_RORN(vB, 0x12F);
    floatx2 a0 = wp[0] * f2(vB);
    floatx2 a1 = wp[1] * f2(t1);
    floatx2 a2 = wp[2] * f2(t2);
    floatx2 a3 = wp[3] * f2(t3);
    a0 = __builtin_elementwise_fma(wp[4],  f2(t4), a0);
    a1 = __builtin_elementwise_fma(wp[5],  f2(t5), a1);
    a2 = __builtin_elementwise_fma(wp[6],  f2(t6), a2);
    a3 = __builtin_elementwise_fma(wp[7],  f2(t7), a3);
    a0 = __builtin_elementwise_fma(wp[8],  f2(t8), a0);
    a1 = __builtin_elementwise_fma(wp[9],  f2(t9), a1);
    a2 = __builtin_elementwise_fma(wp[10], f2(tA), a2);
    a3 = __builtin_elementwise_fma(wp[11], f2(tB), a3);
    a0 = __builtin_elementwise_fma(wp[12], f2(tC), a0);
    a1 = __builtin_elementwise_fma(wp[13], f2(tD), a1);
    a2 = __builtin_elementwise_fma(wp[14], f2(tE), a2);
    a3 = __builtin_elementwise_fma(wp[15], f2(tF), a3);
    return (a0 + a1) + (a2 + a3);
}

// Critical-wave step. Bit-identical core math to the previous kernel; x-park
// and off-path softmax moved to the helper wave. XPEXPR = XP(q+1) from LDS
// (precomputed a full chunk ahead by wave1 -> no exposed latency).
#define STEP0(qv, S1, S2, S3, DO_OUT, XPEXPR)                                     \
  {                                                                               \
    const int q_ = (qv);                                                          \
    float o0v = elur(XZ);                                                         \
    float v0B = TOB(o0v);                                                         \
    floatx2 d1 = rotdot16x2p(v0B, w1p);                                           \
    float o1v = elur(xhalfsum(d1.x + P1[S1]));                                    \
    P1[S1] = b1h + d1.y;                                                          \
    float v1B = TOB(o1v);                                                         \
    floatx2 d2 = rotdot16x2p(v1B, w2p);                                           \
    float o2v = elur(xhalfsum(d2.x + P2[S2]));                                    \
    P2[S2] = b2h + d2.y;                                                          \
    float v2B = TOB(o2v);                                                         \
    floatx2 d3 = rotdot16x2p(v2B, w3p);                                           \
    float a3m = elur(xhalfsum(d3.x + P3[S3]));                                    \
    P3[S3] = b3h + d3.y;                                                          \
    if (DO_OUT) {                                                                 \
      amring[(q_) & 15][lane] = a3m;                                              \
      float g2_own = XGg[((q_ - 15) >> 6) & 1][(q_ - 15) & 63][o3];               \
      float F = fexp2(fmaf(a3m, klog, g2_own));                                   \
      float S = F; RED8_SUM(S);                                                   \
      float r2 = frcp(S);                                                         \
      float rt1 = DPP_RORN(F, 0x121), rt2 = DPP_RORN(F, 0x122);                   \
      float rt3 = DPP_RORN(F, 0x123), rt4 = DPP_RORN(F, 0x124);                   \
      float rt5 = DPP_RORN(F, 0x125), rt6 = DPP_RORN(F, 0x126);                   \
      float rt7 = DPP_RORN(F, 0x127);                                             \
      float na = wznrot[0] * F,   nb = wznrot[1] * rt1;                           \
      float nc = wznrot[2] * rt2, nd = wznrot[3] * rt3;                           \
      na = fmaf(wznrot[4], rt4, na); nb = fmaf(wznrot[5], rt5, nb);               \
      nc = fmaf(wznrot[6], rt6, nc); nd = fmaf(wznrot[7], rt7, nd);               \
      float oa = wzorot[0] * F,   ob = wzorot[1] * rt1;                           \
      float oc = wzorot[2] * rt2, od = wzorot[3] * rt3;                           \
      oa = fmaf(wzorot[4], rt4, oa); ob = fmaf(wzorot[5], rt5, ob);               \
      oc = fmaf(wzorot[6], rt6, oc); od = fmaf(wzorot[7], rt7, od);               \
      ZN   = ((na + nb) + (nc + nd)) * r2;                                        \
      ZQ2n = ((oa + ob) + (oc + od)) * r2;                                        \
    }                                                                             \
    XZ = ((XPEXPR) + ZQ2) + ZN;                                                   \
    ZQ2 = ZQ2n;                                                                   \
  }

// Helper-wave output step for original step p: recompute F (bit-identical
// inputs from LDS) + log-softmax, do the global stores.
#define ROLEA(pv)                                                                 \
  {                                                                               \
    const int p_ = (pv);                                                          \
    float a3 = amring[(p_) & 15][lane];                                           \
    float g2 = XGg[((p_ - 15) >> 6) & 1][(p_ - 15) & 63][o3];                     \
    float F = fexp2(fmaf(a3, klog, g2));                                          \
    float S = F; RED8_SUM(S);                                                     \
    float r2 = frcp(S);                                                           \
    float mx = a3; RED8_MAX(mx);                                                  \
    float e = fexp(a3 - mx);                                                      \
    float se = e; RED8_SUM(se);                                                   \
    float lse = mx + flog(se);                                                    \
    if (lane < 8) {                                                               \
      outg[zoff + lane * TLEN + p_ + 1]       = F * r2;                           \
      outg[qoff + lane * NSTEPS + (p_ - 15)]  = a3 - lse;                         \
    }                                                                             \
  }

__global__ __launch_bounds__(128, 1)
void regime_scan_kernel(const float* __restrict__ xg,
                        const float* __restrict__ tempg,
                        const float* __restrict__ ug,
                        const float* __restrict__ w0g,
                        const float* __restrict__ b0g,
                        const float* __restrict__ w1g,
                        const float* __restrict__ b1g,
                        const float* __restrict__ w2g,
                        const float* __restrict__ b2g,
                        const float* __restrict__ w3g,
                        const float* __restrict__ b3g,
                        float* __restrict__ outg)
{
    __shared__ __align__(16) float xring[80 * 8];       // 2.5 KB (wave1 private)
    __shared__ __align__(16) float XGx[2][64][32];      // 16 KB: XP(q), chunk dbuf
    __shared__ __align__(16) float XGg[2][64][8];       // 2 KB: g2(q), chunk dbuf
    __shared__ __align__(16) float XPwarm[15][32];      // XP(1..14)
    __shared__ __align__(16) float amring[16][64];      // a3m handoff ring

    const int lane = threadIdx.x & 63;
    const int wid  = threadIdx.x >> 6;
    const int b    = blockIdx.x;
    const int c    = lane & 31;
    const int o3   = lane & 7;
    const int tap  = (lane < 32) ? 1 : 0;
    const int s    = lane & 15;
    const int rowq = lane >> 4;
    const int jbase = ((rowq ^ (rowq >> 1)) & 1) << 4;

    // runtime probes
    int dir;
    {
        int l15 = lane & 15;
        int rr1 = __builtin_amdgcn_mov_dpp(l15, 0x121, 0xF, 0xF, false);
        dir = (rr1 == ((l15 + 1) & 15)) ? 1 : -1;
    }
    int selr0 = 0;
#ifdef HAVE_PL16SWAP
    {
        unsigned li = (unsigned)lane;
        uint2v pr = __builtin_amdgcn_permlane16_swap(li, li, false, false);
        selr0 = (pr[0] == (li ^ 16u)) ? 1 : 0;
    }
#endif

    const float tinv = frcp(tempg[0]);
    const float klog = tinv * INVLN2f;
    const int zoff = b * (NK * TLEN);
    const int qoff = NB * NK * TLEN + b * (NK * NSTEPS);

    if (wid == 0) {
        // ================= critical wave =================
        float wznrot[8], wzorot[8];
        #pragma unroll
        for (int r = 0; r < 8; ++r) {
            int ch = (o3 + dir * r) & 7;
            wznrot[r] = w0g[c * 32 + (8 + ch) * 2 + 1];
            wzorot[r] = w0g[c * 32 + (8 + ch) * 2 + 0];
        }
        floatx2 w1p[16], w2p[16], w3p[16];
        #pragma unroll
        for (int r = 0; r < 16; ++r) {
            int jj = jbase + ((s + dir * r) & 15);
            w1p[r].x = w1g[c  * 64 + jj * 2 + 1];
            w1p[r].y = w1g[c  * 64 + jj * 2 + 0];
            w2p[r].x = w2g[c  * 64 + jj * 2 + 1];
            w2p[r].y = w2g[c  * 64 + jj * 2 + 0];
            w3p[r].x = w3g[o3 * 64 + jj * 2 + 1];
            w3p[r].y = w3g[o3 * 64 + jj * 2 + 0];
        }
        const float b1h = 0.5f * b1g[c];
        const float b2h = 0.5f * b2g[c];
        const float b3h = 0.5f * b3g[o3];

        __syncthreads();   // barrier0: wave1 prologue fills done

        float P1[2] = { b1h, b1h };
        float P2[4] = { b2h, b2h, b2h, b2h };
        float P3[8];
        #pragma unroll
        for (int k = 0; k < 8; ++k) P3[k] = b3h;
        float ZQ2 = 0.f, ZQ2n = 0.f, ZN = 0.f;
        float XZ = XPwarm[1][c];

        // warmup q=1..14 (no outputs, feedback zero)
        #pragma unroll
        for (int q = 1; q <= 14; ++q) {
            STEP0(q, q & 1, q & 3, q & 7, 0,
                  (q < 14 ? XPwarm[q + 1][c] : XGx[0][0][c]));
        }
        __syncthreads();   // warmup barrier

        // main: 62 blocks of 8 steps, one barrier per block
        for (int j = 0; j < 62; ++j) {
            const int qb = 15 + 8 * j;
            #pragma unroll
            for (int u = 0; u < 8; ++u) {
                STEP0(qb + u, (15 + u) & 1, (15 + u) & 3, (15 + u) & 7, 1,
                      XGx[((qb + u - 14) >> 6) & 1][(qb + u - 14) & 63][c]);
            }
            __syncthreads();
        }
    } else {
        // ================= helper wave =================
        float wxr[8];
        #pragma unroll
        for (int d = 0; d < 8; ++d) wxr[d] = w0g[c * 32 + d * 2 + tap];
        const float b0r = b0g[c];
        const float* xb = xg + b * (ND * TLEN);

        // ---- prologue: x ring cols 0..79 (l == col) ----
        for (int idx = lane; idx < 80 * ND; idx += 64) {
            int l = idx >> 3, d = idx & 7;
            int t = l - 15;
            xring[idx] = (t >= 0) ? xb[d * TLEN + t] : 0.f;
        }
        // XP(1..14) -> XPwarm; XP(15..78) -> XGx[0]
        for (int it = 0; it <= 77; ++it) {
            const float4* xq = (const float4*)&xring[(it + tap) * 8];
            float4 xa = xq[0], xbv = xq[1];
            float s0 = fmaf(wxr[0], xa.x, fmaf(wxr[1], xa.y, 0.f));
            float s1 = fmaf(wxr[2], xa.z, fmaf(wxr[3], xa.w, 0.f));
            float s2 = fmaf(wxr[4], xbv.x, fmaf(wxr[5], xbv.y, 0.f));
            float s3 = fmaf(wxr[6], xbv.z, fmaf(wxr[7], xbv.w, 0.f));
            float h = xhalfsum((s0 + s1) + (s2 + s3)) + b0r;
            if (lane < 32) {
                if (it < 14) XPwarm[it + 1][c] = h;
                else         XGx[0][it - 14][c] = h;
            }
        }
        // g2 chunk 0 (steps 0..63)
        for (int idx = lane; idx < 64 * NK; idx += 64) {
            int st = idx >> 3, kk = idx & 7;
            float uu = ug[st * (NB * NK) + b * NK + kk];
            XGg[0][idx >> 3][kk] = -flog(-flog(uu + 1e-10f) + 1e-10f) * klog;
        }
        // z_all[:, :, 0:16] = 0
        for (int idx = lane; idx < NK * 16; idx += 64) {
            outg[zoff + (idx >> 4) * TLEN + (idx & 15)] = 0.f;
        }

        __syncthreads();   // barrier0
        __syncthreads();   // warmup barrier (wave1 idle in warmup)

        for (int j = 0; j < 62; ++j) {
            // outputs for previous block's steps
            if (j >= 1) {
                const int p0 = 7 + 8 * j;
                #pragma unroll
                for (int u = 0; u < 8; ++u) ROLEA(p0 + u);
            }
            // x ring refill for chunk cn = (j>>3)+1 at block 8k
            if ((j & 7) == 0 && j <= 48) {
                const int cn = (j >> 3) + 1;
                const int base = 14 + 64 * cn;
                for (int idx = lane; idx < 66 * ND; idx += 64) {
                    int l = idx >> 3, d = idx & 7;
                    int t = base + l - 15;
                    xring[idx] = (t < TLEN) ? xb[d * TLEN + t] : 0.f;
                }
            }
            // XP + g2 fill for chunk cn at block 8k+1
            if ((j & 7) == 1 && j <= 49) {
                const int cn = (j >> 3) + 1;
                const int kb = cn & 1;
                for (int i = 0; i < 64; ++i) {
                    const float4* xq = (const float4*)&xring[(i + tap) * 8];
                    float4 xa = xq[0], xbv = xq[1];
                    float s0 = fmaf(wxr[0], xa.x, fmaf(wxr[1], xa.y, 0.f));
                    float s1 = fmaf(wxr[2], xa.z, fmaf(wxr[3], xa.w, 0.f));
                    float s2 = fmaf(wxr[4], xbv.x, fmaf(wxr[5], xbv.y, 0.f));
                    float s3 = fmaf(wxr[6], xbv.z, fmaf(wxr[7], xbv.w, 0.f));
                    float h = xhalfsum((s0 + s1) + (s2 + s3)) + b0r;
                    if (lane < 32) XGx[kb][i][c] = h;
                }
                for (int idx = lane; idx < 64 * NK; idx += 64) {
                    int st = 64 * cn + (idx >> 3), kk = idx & 7;
                    float v = 0.f;
                    if (st < NSTEPS) {
                        float uu = ug[st * (NB * NK) + b * NK + kk];
                        v = -flog(-flog(uu + 1e-10f) + 1e-10f) * klog;
                    }
                    XGg[kb][idx >> 3][kk] = v;
                }
            }
            __syncthreads();
        }
        // epilogue: outputs for the final block p=503..510
        {
            #pragma unroll
            for (int u = 0; u < 8; ++u) ROLEA(503 + u);
        }
    }
}

extern "C" void kernel_launch(void* const* d_in, const int* in_sizes, int n_in,
                              void* d_out, int out_size, void* d_ws, size_t ws_size,
                              hipStream_t stream) {
    (void)in_sizes; (void)n_in; (void)out_size; (void)d_ws; (void)ws_size;
    regime_scan_kernel<<<dim3(NB), dim3(128), 0, stream>>>(
        (const float*)d_in[0],   // x
        (const float*)d_in[1],   // temp
        (const float*)d_in[2],   // u
        (const float*)d_in[3],   // w0
        (const float*)d_in[4],   // b0
        (const float*)d_in[5],   // w1
        (const float*)d_in[6],   // b1
        (const float*)d_in[7],   // w2
        (const float*)d_in[8],   // b2
        (const float*)d_in[9],   // w3
        (const float*)d_in[10],  // b3
        (float*)d_out);
}